// Round 1
// baseline (163.561 us; speedup 1.0000x reference)
//
#include <hip/hip_runtime.h>

// CNN_pre_LSTM: per-sample pipeline
//   x(1,24) -> conv11(8,K3)+ReLU -> conv12(8,K3)+ReLU -> pool2
//          -> conv21(16,K3)+ReLU -> conv22(16,K3)+ReLU -> pool2 -> Linear(96->24)
// 131072 samples. Block = 256 threads = 4 waves, 64 samples/block, lane = sample.
// Wave w owns an output-channel group -> weight indices are wave-uniform (SGPR).
// LDS feature maps laid out [ch][pos][sample64]: conflict-free ds_read/write.

#define TPB 256

__launch_bounds__(TPB, 2)
__global__ void cnn_pre_lstm_kernel(
    const float* __restrict__ x,
    const float* __restrict__ w11, const float* __restrict__ b11,
    const float* __restrict__ w12, const float* __restrict__ b12,
    const float* __restrict__ w21, const float* __restrict__ b21,
    const float* __restrict__ w22, const float* __restrict__ b22,
    const float* __restrict__ Wl,  const float* __restrict__ bl,
    float* __restrict__ out)
{
    __shared__ float sA[12288];  // 48 KB: h1 [8][24][64] / h3 [16][12][64] / outbuf [1536]
    __shared__ float sB[6144];   // 24 KB: xbuf [64][25] / h2p [8][12][64] / h4p [16][6][64]

    const int tid = threadIdx.x;
    const int ln  = tid & 63;
    const int wv  = __builtin_amdgcn_readfirstlane(tid >> 6);  // wave id 0..3, forced SGPR

    // ---------------- Stage 0: coalesced load of 64 samples of x into LDS ----
    {
        const float* xg = x + (size_t)blockIdx.x * (64 * 24);
        #pragma unroll
        for (int k = 0; k < 6; ++k) {
            int o = tid + k * TPB;           // 0..1535
            int s = o / 24, p = o % 24;
            sB[s * 25 + p] = xg[o];          // padded row 25: conflict-free reads later
        }
    }
    __syncthreads();

    // ---------------- Stage 1: conv11 (1->8, K=3, pad1) + ReLU ---------------
    // wave w computes co in {2w, 2w+1}; h1 -> sA [8][24][64]
    {
        const int co0 = wv * 2;
        float wA0 = w11[co0*3+0], wA1 = w11[co0*3+1], wA2 = w11[co0*3+2];
        float wB0 = w11[(co0+1)*3+0], wB1 = w11[(co0+1)*3+1], wB2 = w11[(co0+1)*3+2];
        float bA = b11[co0], bB = b11[co0+1];

        float xm = 0.f, xc = sB[ln*25 + 0], xp;
        #pragma unroll
        for (int p = 0; p < 24; ++p) {
            xp = (p < 23) ? sB[ln*25 + p + 1] : 0.f;
            float a = fmaf(wA0, xm, fmaf(wA1, xc, fmaf(wA2, xp, bA)));
            float b = fmaf(wB0, xm, fmaf(wB1, xc, fmaf(wB2, xp, bB)));
            sA[ co0      * 1536 + p * 64 + ln] = fmaxf(a, 0.f);
            sA[(co0 + 1) * 1536 + p * 64 + ln] = fmaxf(b, 0.f);
            xm = xc; xc = xp;
        }
    }
    __syncthreads();

    // ---------------- Stage 2: conv12 (8->8) + ReLU + pool2 ------------------
    // wave w: co in {2w,2w+1}; reads h1 (sA), writes h2p -> sB [8][12][64]
    {
        const int co0 = wv * 2;
        float acc[2][24];
        #pragma unroll
        for (int i = 0; i < 2; ++i) {
            float bb = b12[co0 + i];
            #pragma unroll
            for (int p = 0; p < 24; ++p) acc[i][p] = bb;
        }
        for (int ci = 0; ci < 8; ++ci) {
            float wg[2][3];
            #pragma unroll
            for (int i = 0; i < 2; ++i) {
                const float* wp = w12 + ((co0 + i) * 8 + ci) * 3;
                wg[i][0] = wp[0]; wg[i][1] = wp[1]; wg[i][2] = wp[2];
            }
            const int cb = ci * 1536 + ln;
            float xm = 0.f, xc = sA[cb], xp;
            #pragma unroll
            for (int p = 0; p < 24; ++p) {
                xp = (p < 23) ? sA[cb + (p + 1) * 64] : 0.f;
                #pragma unroll
                for (int i = 0; i < 2; ++i)
                    acc[i][p] = fmaf(wg[i][0], xm, fmaf(wg[i][1], xc, fmaf(wg[i][2], xp, acc[i][p])));
                xm = xc; xc = xp;
            }
        }
        #pragma unroll
        for (int i = 0; i < 2; ++i)
            #pragma unroll
            for (int p2 = 0; p2 < 12; ++p2)
                sB[(co0 + i) * 768 + p2 * 64 + ln] =
                    fmaxf(fmaxf(acc[i][2*p2], acc[i][2*p2+1]), 0.f);
    }
    __syncthreads();

    // ---------------- Stage 3: conv21 (8->16) + ReLU -------------------------
    // wave w: co in {4w..4w+3}; reads h2p (sB), writes h3 -> sA [16][12][64]
    {
        const int co0 = wv * 4;
        float acc[4][12];
        #pragma unroll
        for (int i = 0; i < 4; ++i) {
            float bb = b21[co0 + i];
            #pragma unroll
            for (int p = 0; p < 12; ++p) acc[i][p] = bb;
        }
        for (int ci = 0; ci < 8; ++ci) {
            float wg[4][3];
            #pragma unroll
            for (int i = 0; i < 4; ++i) {
                const float* wp = w21 + ((co0 + i) * 8 + ci) * 3;
                wg[i][0] = wp[0]; wg[i][1] = wp[1]; wg[i][2] = wp[2];
            }
            const int cb = ci * 768 + ln;
            float xm = 0.f, xc = sB[cb], xp;
            #pragma unroll
            for (int p = 0; p < 12; ++p) {
                xp = (p < 11) ? sB[cb + (p + 1) * 64] : 0.f;
                #pragma unroll
                for (int i = 0; i < 4; ++i)
                    acc[i][p] = fmaf(wg[i][0], xm, fmaf(wg[i][1], xc, fmaf(wg[i][2], xp, acc[i][p])));
                xm = xc; xc = xp;
            }
        }
        #pragma unroll
        for (int i = 0; i < 4; ++i)
            #pragma unroll
            for (int p = 0; p < 12; ++p)
                sA[(co0 + i) * 768 + p * 64 + ln] = fmaxf(acc[i][p], 0.f);
    }
    __syncthreads();

    // ---------------- Stage 4: conv22 (16->16) + ReLU + pool2 ----------------
    // wave w: co in {4w..4w+3}; reads h3 (sA), writes h4p -> sB [16][6][64]
    {
        const int co0 = wv * 4;
        float acc[4][12];
        #pragma unroll
        for (int i = 0; i < 4; ++i) {
            float bb = b22[co0 + i];
            #pragma unroll
            for (int p = 0; p < 12; ++p) acc[i][p] = bb;
        }
        for (int ci = 0; ci < 16; ++ci) {
            float wg[4][3];
            #pragma unroll
            for (int i = 0; i < 4; ++i) {
                const float* wp = w22 + ((co0 + i) * 16 + ci) * 3;
                wg[i][0] = wp[0]; wg[i][1] = wp[1]; wg[i][2] = wp[2];
            }
            const int cb = ci * 768 + ln;
            float xm = 0.f, xc = sA[cb], xp;
            #pragma unroll
            for (int p = 0; p < 12; ++p) {
                xp = (p < 11) ? sA[cb + (p + 1) * 64] : 0.f;
                #pragma unroll
                for (int i = 0; i < 4; ++i)
                    acc[i][p] = fmaf(wg[i][0], xm, fmaf(wg[i][1], xc, fmaf(wg[i][2], xp, acc[i][p])));
                xm = xc; xc = xp;
            }
        }
        #pragma unroll
        for (int i = 0; i < 4; ++i)
            #pragma unroll
            for (int p2 = 0; p2 < 6; ++p2)
                sB[(co0 + i) * 384 + p2 * 64 + ln] =
                    fmaxf(fmaxf(acc[i][2*p2], acc[i][2*p2+1]), 0.f);
    }
    __syncthreads();

    // ---------------- Stage 5: Linear (96 -> 24) -----------------------------
    // feature f = c*6 + p (torch reshape order). wave w: out j in {6w..6w+5}.
    {
        const int j0 = wv * 6;
        float acc6[6];
        #pragma unroll
        for (int i = 0; i < 6; ++i) acc6[i] = bl[j0 + i];
        for (int c = 0; c < 16; ++c) {
            #pragma unroll
            for (int p = 0; p < 6; ++p) {
                float v = sB[c * 384 + p * 64 + ln];
                const int f = c * 6 + p;
                #pragma unroll
                for (int i = 0; i < 6; ++i)
                    acc6[i] = fmaf(Wl[(j0 + i) * 96 + f], v, acc6[i]);
            }
        }
        #pragma unroll
        for (int i = 0; i < 6; ++i)
            sA[ln * 24 + j0 + i] = acc6[i];
    }
    __syncthreads();

    // ---------------- Stage 6: coalesced store -------------------------------
    {
        float* og = out + (size_t)blockIdx.x * (64 * 24);
        #pragma unroll
        for (int k = 0; k < 6; ++k) {
            int o = tid + k * TPB;
            og[o] = sA[o];
        }
    }
}

extern "C" void kernel_launch(void* const* d_in, const int* in_sizes, int n_in,
                              void* d_out, int out_size, void* d_ws, size_t ws_size,
                              hipStream_t stream) {
    const float* x   = (const float*)d_in[0];
    const float* w11 = (const float*)d_in[1];
    const float* b11 = (const float*)d_in[2];
    const float* w12 = (const float*)d_in[3];
    const float* b12 = (const float*)d_in[4];
    const float* w21 = (const float*)d_in[5];
    const float* b21 = (const float*)d_in[6];
    const float* w22 = (const float*)d_in[7];
    const float* b22 = (const float*)d_in[8];
    const float* Wl  = (const float*)d_in[9];
    const float* bl  = (const float*)d_in[10];
    float* out = (float*)d_out;

    const int n_samples = in_sizes[0] / 24;    // 512*256 = 131072
    const int blocks = n_samples / 64;         // 2048

    hipLaunchKernelGGL(cnn_pre_lstm_kernel, dim3(blocks), dim3(TPB), 0, stream,
                       x, w11, b11, w12, b12, w21, b21, w22, b22, Wl, bl, out);
}